// Round 8
// baseline (1126.895 us; speedup 1.0000x reference)
//
#include <hip/hip_runtime.h>

// LSTMDecoder: B=256, D=512, T=64, 2 layers. Persistent cooperative kernel
// (R5 skeleton: 256 WGs x 256 thr, LDS fp16 weights in MFMA B-frag order,
// c-state in registers, 4 batch-groups x 64 WGs, slot-flag sync).
// R8: h rotates through 128 per-stage buffers in ws (no address ever reused),
// producers store sc0 sc1 (IF$), consumers use PLAIN CACHED loads — each 128B
// line is IF$-fetched once per XCD then L2/L1-served to the ~8 co-located
// group WGs. R5 was fabric-bound: sc-bypass 16B gathers, 16 MB/stage, zero
// reuse. Correctness: kernel-start acquire invalidates caches; within the
// kernel each rot address is written once (drained pre-flag) and read after.
// Fallback (ws too small): 4-deep ring + sc1 loads = R5 semantics.
// R6/R7 lesson kept: no register-resident weights (cooperative validation
// fails ~400 VGPR), no plain-launch grid spin (deadlocks — co-residency is
// only guaranteed by hipLaunchCooperativeKernel).

#define BD    131072                      // B*D elements
#define SMEM_WBYTES 131072                // 2 layers * 32 gate-rows * 1024 K * 2B
#define SMEM_BYTES  (SMEM_WBYTES + 4 * 1056 * 4)   // + red[4][32][33] f32

#define WS_SLOTS 0                        // 4 groups * 64 packed uint flags
#define WS_XINIT 4096
#define WS_ZERO  (WS_XINIT + BD * 2)
#define WS_ROT   (WS_ZERO + BD * 2)
#define ROT_BYTES ((size_t)BD * 2)        // 256 KB per stage buffer
#define WS_NEED_DEEP (WS_ROT + 128 * ROT_BYTES)   // ~33.8 MB
#define WS_NEED_RING (WS_ROT + 4 * ROT_BYTES)

typedef _Float16 half8_t  __attribute__((ext_vector_type(8)));
typedef float    f32x16_t __attribute__((ext_vector_type(16)));
typedef float    f32x4_t  __attribute__((ext_vector_type(4)));

#define LOADC(p)  __hip_atomic_load((p), __ATOMIC_RELAXED, __HIP_MEMORY_SCOPE_AGENT)
#define STOREC(p, v) __hip_atomic_store((p), (v), __ATOMIC_RELAXED, __HIP_MEMORY_SCOPE_AGENT)

__device__ __forceinline__ float sigmoidf_(float x) {
  float z = __expf(-fabsf(x));
  float s = 1.0f / (1.0f + z);
  return x >= 0.0f ? s : 1.0f - s;
}
__device__ __forceinline__ float tanhf_(float x) {
  float z = __expf(-2.0f * fabsf(x));
  float t = (1.0f - z) / (1.0f + z);
  return x >= 0.0f ? t : -t;
}

// system-scope (IF$) load for the fallback path; caller waits vmcnt(0).
__device__ __forceinline__ f32x4_t load_cv16(const void* p) {
  f32x4_t r;
  asm volatile("global_load_dwordx4 %0, %1, off sc0 sc1"
               : "=v"(r) : "v"(p) : "memory");
  return r;
}

__global__ void lstm_init(const float* __restrict__ h, char* __restrict__ ws) {
  int i = blockIdx.x * 256 + threadIdx.x;
  unsigned* slots = (unsigned*)(ws + WS_SLOTS);
  _Float16* xinit = (_Float16*)(ws + WS_XINIT);
  _Float16* zerob = (_Float16*)(ws + WS_ZERO);
  if (i < BD) {
    xinit[i] = (_Float16)h[i];
    zerob[i] = (_Float16)0.0f;
  }
  if (i < 256) slots[i] = 0u;
}

__global__ void __launch_bounds__(256, 1) lstm_persist(
    const float* __restrict__ Wih0, const float* __restrict__ Whh0,
    const float* __restrict__ bih0, const float* __restrict__ bhh0,
    const float* __restrict__ Wih1, const float* __restrict__ Whh1,
    const float* __restrict__ bih1, const float* __restrict__ bhh1,
    float* __restrict__ out, char* __restrict__ ws, int deep)
{
  extern __shared__ char smem[];
  float* red = (float*)(smem + SMEM_WBYTES);   // red[4 waves][32 rows][33 pad]
  unsigned* slots = (unsigned*)(ws + WS_SLOTS);
  const _Float16* xinit = (const _Float16*)(ws + WS_XINIT);
  const _Float16* zerob = (const _Float16*)(ws + WS_ZERO);
  char* rot = ws + WS_ROT;

  const int tid = threadIdx.x;
  const int l = tid & 63;
  const int w = tid >> 6;
  const int bid = blockIdx.x;
  const int bb = (bid & 7) >> 1;                       // 0..3 batch group
  const int db = ((bid >> 3) << 1) | (bid & 1);        // 0..63 d block (rank)
  const int b0 = bb << 6;                              // 64 batch rows
  const int d0 = db << 3;                              // 8 d values

  // ---- stage weights (fp32 -> fp16) into LDS in MFMA B-fragment order ----
#pragma unroll
  for (int L = 0; L < 2; ++L) {
    for (int it = 0; it < 16; ++it) {
      int slot = it * 256 + tid;                 // 0..4095
      int s2 = slot >> 6, lane = slot & 63;
      int khalf = s2 >> 5, ks = s2 & 31;
      int kg = lane >> 5, nl = lane & 31;
      int ng = ((nl >> 3) << 9) + d0 + (nl & 7); // gate*512 + d0 + j
      int col = ks * 16 + kg * 8;
      const float* srcb = khalf ? (L ? Whh1 : Whh0) : (L ? Wih1 : Wih0);
      const float* src = srcb + (size_t)ng * 512 + col;
      half8_t hv;
#pragma unroll
      for (int j = 0; j < 8; ++j) hv[j] = (_Float16)src[j];
      *(half8_t*)(smem + (size_t)L * 65536 + (size_t)slot * 16) = hv;
    }
  }

  // ---- bias (b_ih+b_hh) for this thread's two d values (j0, j0+1) ----
  const int cbl = tid >> 2;            // batch row (within group) in cell phase
  const int j0 = (tid & 3) << 1;       // even d offset
  float bias0[4][2], bias1[4][2];
#pragma unroll
  for (int g = 0; g < 4; ++g) {
#pragma unroll
    for (int p = 0; p < 2; ++p) {
      int ng = (g << 9) + d0 + j0 + p;
      bias0[g][p] = bih0[ng] + bhh0[ng];
      bias1[g][p] = bih1[ng] + bhh1[ng];
    }
  }
  float c0s[2] = {0.0f, 0.0f}, c1s[2] = {0.0f, 0.0f};
  unsigned* gflags = slots + (bb << 6);  // 64 packed flags per group
  __syncthreads();

  // ---- 128 sequential stages: s even = layer0, odd = layer1 ----
  // Uniform rotation: stage s writes rot[s]; fresh = rot[s-1]; stale = rot[s-2].
  for (int s = 0; s < 128; ++s) {
    const int t = s >> 1;
    const int layer = s & 1;
    const int fi = deep ? (s - 1) : ((s - 1) & 3);
    const int si = deep ? (s - 2) : ((s - 2) & 3);
    const int oi = deep ? s : (s & 3);
    const _Float16* fresh = (s == 0) ? xinit
                          : (const _Float16*)(rot + (size_t)fi * ROT_BYTES);
    const _Float16* stale = (s <= 1) ? zerob
                          : (const _Float16*)(rot + (size_t)si * ROT_BYTES);
    _Float16* hout = (_Float16*)(rot + (size_t)oi * ROT_BYTES);

    // waves 0,1 (fresh half) wait for group barrier s-1; waves 2,3 run ahead
    if (w < 2 && s > 0) {
      const unsigned* sl = gflags + l;     // lane l polls WG l's flag
      unsigned v;
      do {
        v = LOADC(sl);
      } while (!__all((int)(v >= (unsigned)s)));
      asm volatile("" ::: "memory");       // pin A-loads below the poll
    }

    // ---- GEMM: wave w: M-tile = w&1 (32 b-rows), input-half = w>>1 ----
    const _Float16* asrc = (w >= 2) ? stale : fresh;
    const char* ap = (const char*)(asrc + (size_t)(b0 + ((w & 1) << 5) + (l & 31)) * 512
                                        + ((l >> 5) << 3));
    int boff = layer * 65536 + ((w >> 1) * 32768) + l * 16;

    f32x16_t acc0, acc1;
#pragma unroll
    for (int r = 0; r < 16; ++r) { acc0[r] = 0.0f; acc1[r] = 0.0f; }

    if (deep) {
      // plain cached loads: lines fill L2/L1, shared by co-XCD group WGs.
#pragma unroll
      for (int half = 0; half < 2; ++half) {
        f32x4_t va[16];
#pragma unroll
        for (int j = 0; j < 16; ++j)
          va[j] = *(const f32x4_t*)(ap + half * 512 + 32 * j);
#pragma unroll
        for (int ks = 0; ks < 8; ++ks) {
          half8_t a0  = __builtin_bit_cast(half8_t, va[2 * ks]);
          half8_t a1  = __builtin_bit_cast(half8_t, va[2 * ks + 1]);
          half8_t bv0 = *(const half8_t*)(smem + boff);
          half8_t bv1 = *(const half8_t*)(smem + boff + 1024);
          acc0 = __builtin_amdgcn_mfma_f32_32x32x16_f16(a0, bv0, acc0, 0, 0, 0);
          acc1 = __builtin_amdgcn_mfma_f32_32x32x16_f16(a1, bv1, acc1, 0, 0, 0);
          boff += 2048;
        }
      }
    } else {
      // fallback: system-scope loads (R5 semantics), 2 bursts of 16
#pragma unroll
      for (int half = 0; half < 2; ++half) {
        f32x4_t va[16];
#pragma unroll
        for (int j = 0; j < 16; ++j) va[j] = load_cv16(ap + half * 512 + 32 * j);
        asm volatile("s_waitcnt vmcnt(0)" ::: "memory");
#pragma unroll
        for (int ks = 0; ks < 8; ++ks) {
          half8_t a0  = __builtin_bit_cast(half8_t, va[2 * ks]);
          half8_t a1  = __builtin_bit_cast(half8_t, va[2 * ks + 1]);
          half8_t bv0 = *(const half8_t*)(smem + boff);
          half8_t bv1 = *(const half8_t*)(smem + boff + 1024);
          acc0 = __builtin_amdgcn_mfma_f32_32x32x16_f16(a0, bv0, acc0, 0, 0, 0);
          acc1 = __builtin_amdgcn_mfma_f32_32x32x16_f16(a1, bv1, acc1, 0, 0, 0);
          boff += 2048;
        }
      }
    }

    // ---- C frags -> LDS red[w][row][33] (row = (r&3)+8*(r>>2)+4*(l>>5)) ----
    {
      float* redw = red + w * 1056 + (l & 31);
      const int rbase = (l >> 5) << 2;
#pragma unroll
      for (int r = 0; r < 16; ++r) {
        int row = (r & 3) + ((r >> 2) << 3) + rbase;
        redw[row * 33] = acc0[r] + acc1[r];
      }
    }
    __syncthreads();

    // ---- cell update: thread owns (cbl, j0) and (cbl, j0+1); c in regs ----
    float hv[2];
    int gidx;
    {
      const int base = (cbl >> 5) * 1056 + (cbl & 31) * 33 + j0;
#pragma unroll
      for (int p = 0; p < 2; ++p) {
        float vi = red[base + p]      + red[base + 2112 + p]      + (layer ? bias1[0][p] : bias0[0][p]);
        float vf = red[base + 8 + p]  + red[base + 2112 + 8 + p]  + (layer ? bias1[1][p] : bias0[1][p]);
        float vg = red[base + 16 + p] + red[base + 2112 + 16 + p] + (layer ? bias1[2][p] : bias0[2][p]);
        float vo = red[base + 24 + p] + red[base + 2112 + 24 + p] + (layer ? bias1[3][p] : bias0[3][p]);
        float iv = sigmoidf_(vi), fv = sigmoidf_(vf);
        float gv = tanhf_(vg),    ov = sigmoidf_(vo);
        float cold = layer ? c1s[p] : c0s[p];
        float c = fv * cold + iv * gv;
        if (layer) c1s[p] = c; else c0s[p] = c;
        hv[p] = ov * tanhf_(c);
      }
      gidx = (b0 + cbl) * 512 + d0 + j0;
      unsigned hu = ((unsigned)__builtin_bit_cast(unsigned short, (_Float16)hv[0])) |
                    ((unsigned)__builtin_bit_cast(unsigned short, (_Float16)hv[1]) << 16);
      STOREC((unsigned*)&hout[gidx], hu);            // sc0 sc1 -> IF$, no fence
    }
    asm volatile("s_waitcnt vmcnt(0)" ::: "memory"); // h stores acked at IF$
    __syncthreads();                                  // all threads drained
    if (tid == 0)
      STOREC(gflags + db, (unsigned)(s + 1));        // relaxed release
    if (layer) {                                      // off the critical path
      float* op = out + (size_t)t * BD + gidx;
      op[0] = hv[0]; op[1] = hv[1];
    }
  }
}

extern "C" void kernel_launch(void* const* d_in, const int* in_sizes, int n_in,
                              void* d_out, int out_size, void* d_ws, size_t ws_size,
                              hipStream_t stream) {
  const float* h    = (const float*)d_in[0];
  // d_in[1] = T (== 64, compile-time)
  const float* Wih0 = (const float*)d_in[2];
  const float* Whh0 = (const float*)d_in[3];
  const float* bih0 = (const float*)d_in[4];
  const float* bhh0 = (const float*)d_in[5];
  const float* Wih1 = (const float*)d_in[6];
  const float* Whh1 = (const float*)d_in[7];
  const float* bih1 = (const float*)d_in[8];
  const float* bhh1 = (const float*)d_in[9];
  float* out = (float*)d_out;
  char* ws = (char*)d_ws;

  int deep = (ws_size >= (size_t)WS_NEED_DEEP) ? 1 : 0;

  hipFuncSetAttribute((const void*)lstm_persist,
                      hipFuncAttributeMaxDynamicSharedMemorySize, SMEM_BYTES);

  lstm_init<<<512, 256, 0, stream>>>(h, ws);

  void* args[] = { &Wih0, &Whh0, &bih0, &bhh0, &Wih1, &Whh1, &bih1, &bhh1,
                   &out, &ws, &deep };
  hipLaunchCooperativeKernel((void*)lstm_persist, dim3(256), dim3(256),
                             args, SMEM_BYTES, stream);
}

// Round 9
// 921.490 us; speedup vs baseline: 1.2229x; 1.2229x over previous
//
#include <hip/hip_runtime.h>

// LSTMDecoder: B=256, D=512, T=64, 2 layers. Persistent kernel, PLAIN launch.
// R9: sentinel-polled dataflow — NO flags, NO producer-side sync at all.
// h rotates through 128 per-stage buffers (R8 evidence: ws >= 34 MB), init
// pre-fills them with 0xFFFFFFFF (fp16 NaN pair — unreachable from any
// (_Float16)(finite) cast). Producers store h sc0 sc1 (MALL); consumers
// burst-load their fresh A-half and retry until no dword == sentinel
// (4B stores are dword-atomic, so per-dword check is exact). Stale half
// (rot[s-2]) needs no check: this WG's stage s-1 fresh-check validated it,
// ordered by the intra-WG barrier. No inter-WG waits by producers and no
// grid barriers => dispatch-order-safe => plain launch (no cooperative
// validation, no co-residency spin — the R6/R7 failure class is gone).
// R5's skeleton otherwise: 4 batch-groups x 64 WGs, 8 d/WG, fp16 weights in
// LDS (MFMA B-frag order), c-state in registers, cell via LDS red[].

#define BD    131072                      // B*D elements
#define SMEM_WBYTES 131072                // 2 layers * 32 gate-rows * 1024 K * 2B
#define SMEM_BYTES  (SMEM_WBYTES + 4 * 1056 * 4)   // + red[4][32][33] f32

#define WS_XINIT 4096
#define WS_ZERO  (WS_XINIT + BD * 2)
#define WS_ROT   (WS_ZERO + BD * 2)
#define ROT_BYTES ((size_t)BD * 2)        // 256 KB per stage buffer
#define WS_NEED  (WS_ROT + 128 * ROT_BYTES)   // 34082816 B (~32.5 MiB)

typedef _Float16 half8_t  __attribute__((ext_vector_type(8)));
typedef float    f32x16_t __attribute__((ext_vector_type(16)));
typedef float    f32x4_t  __attribute__((ext_vector_type(4)));
typedef unsigned uint4_t  __attribute__((ext_vector_type(4)));

#define STOREC(p, v) __hip_atomic_store((p), (v), __ATOMIC_RELAXED, __HIP_MEMORY_SCOPE_AGENT)

__device__ __forceinline__ float sigmoidf_(float x) {
  float z = __expf(-fabsf(x));
  float s = 1.0f / (1.0f + z);
  return x >= 0.0f ? s : 1.0f - s;
}
__device__ __forceinline__ float tanhf_(float x) {
  float z = __expf(-2.0f * fabsf(x));
  float t = (1.0f - z) / (1.0f + z);
  return x >= 0.0f ? t : -t;
}

// system-scope (MALL-coherent) 16B load; caller must s_waitcnt vmcnt(0).
__device__ __forceinline__ f32x4_t load_cv16(const void* p) {
  f32x4_t r;
  asm volatile("global_load_dwordx4 %0, %1, off sc0 sc1"
               : "=v"(r) : "v"(p) : "memory");
  return r;
}

__global__ void lstm_init(const float* __restrict__ h, char* __restrict__ ws) {
  int i = blockIdx.x * 256 + threadIdx.x;          // grid 2048*256 = 524288
  _Float16* xinit = (_Float16*)(ws + WS_XINIT);
  _Float16* zerob = (_Float16*)(ws + WS_ZERO);
  if (i < BD) {
    xinit[i] = (_Float16)h[i];
    zerob[i] = (_Float16)0.0f;
  }
  // sentinel-fill the 128 rotation buffers: 33554432 B = 2097152 uint4
  uint4_t* rot4 = (uint4_t*)(ws + WS_ROT);
  uint4_t s4; s4[0] = 0xFFFFFFFFu; s4[1] = 0xFFFFFFFFu;
  s4[2] = 0xFFFFFFFFu; s4[3] = 0xFFFFFFFFu;
  for (int j = i; j < 2097152; j += 524288) rot4[j] = s4;
}

__global__ void __launch_bounds__(256, 1) lstm_persist(
    const float* __restrict__ Wih0, const float* __restrict__ Whh0,
    const float* __restrict__ bih0, const float* __restrict__ bhh0,
    const float* __restrict__ Wih1, const float* __restrict__ Whh1,
    const float* __restrict__ bih1, const float* __restrict__ bhh1,
    float* __restrict__ out, char* __restrict__ ws)
{
  extern __shared__ char smem[];
  float* red = (float*)(smem + SMEM_WBYTES);   // red[4 waves][32 rows][33 pad]
  const _Float16* xinit = (const _Float16*)(ws + WS_XINIT);
  const _Float16* zerob = (const _Float16*)(ws + WS_ZERO);
  char* rot = ws + WS_ROT;

  const int tid = threadIdx.x;
  const int l = tid & 63;
  const int w = tid >> 6;
  const int bid = blockIdx.x;
  const int bb = (bid & 7) >> 1;                       // 0..3 batch group
  const int db = ((bid >> 3) << 1) | (bid & 1);        // 0..63 d block
  const int b0 = bb << 6;                              // 64 batch rows
  const int d0 = db << 3;                              // 8 d values

  // ---- stage weights (fp32 -> fp16) into LDS in MFMA B-fragment order ----
#pragma unroll
  for (int L = 0; L < 2; ++L) {
    for (int it = 0; it < 16; ++it) {
      int slot = it * 256 + tid;                 // 0..4095
      int s2 = slot >> 6, lane = slot & 63;
      int khalf = s2 >> 5, ks = s2 & 31;
      int kg = lane >> 5, nl = lane & 31;
      int ng = ((nl >> 3) << 9) + d0 + (nl & 7); // gate*512 + d0 + j
      int col = ks * 16 + kg * 8;
      const float* srcb = khalf ? (L ? Whh1 : Whh0) : (L ? Wih1 : Wih0);
      const float* src = srcb + (size_t)ng * 512 + col;
      half8_t hv;
#pragma unroll
      for (int j = 0; j < 8; ++j) hv[j] = (_Float16)src[j];
      *(half8_t*)(smem + (size_t)L * 65536 + (size_t)slot * 16) = hv;
    }
  }

  // ---- bias (b_ih+b_hh) for this thread's two d values (j0, j0+1) ----
  const int cbl = tid >> 2;            // batch row (within group) in cell phase
  const int j0 = (tid & 3) << 1;       // even d offset
  float bias0[4][2], bias1[4][2];
#pragma unroll
  for (int g = 0; g < 4; ++g) {
#pragma unroll
    for (int p = 0; p < 2; ++p) {
      int ng = (g << 9) + d0 + j0 + p;
      bias0[g][p] = bih0[ng] + bhh0[ng];
      bias1[g][p] = bih1[ng] + bhh1[ng];
    }
  }
  float c0s[2] = {0.0f, 0.0f}, c1s[2] = {0.0f, 0.0f};
  __syncthreads();

  // ---- 128 sequential stages: s even = layer0, odd = layer1 ----
  // stage s writes rot[s]; fresh input = rot[s-1]; stale half = rot[s-2].
  for (int s = 0; s < 128; ++s) {
    const int t = s >> 1;
    const int layer = s & 1;
    const _Float16* fresh = (s == 0) ? xinit
                          : (const _Float16*)(rot + (size_t)(s - 1) * ROT_BYTES);
    const _Float16* stale = (s <= 1) ? zerob
                          : (const _Float16*)(rot + (size_t)(s - 2) * ROT_BYTES);
    _Float16* hout = (_Float16*)(rot + (size_t)s * ROT_BYTES);

    // ---- GEMM: wave w: M-tile = w&1 (32 b-rows), input-half = w>>1 ----
    const _Float16* asrc = (w >= 2) ? stale : fresh;
    const char* ap = (const char*)(asrc + (size_t)(b0 + ((w & 1) << 5) + (l & 31)) * 512
                                        + ((l >> 5) << 3));
    const bool needcheck = (w < 2) && (s > 0);
    int boff = layer * 65536 + ((w >> 1) * 32768) + l * 16;

    f32x16_t acc0, acc1;
#pragma unroll
    for (int r = 0; r < 16; ++r) { acc0[r] = 0.0f; acc1[r] = 0.0f; }

#pragma unroll
    for (int half = 0; half < 2; ++half) {
      f32x4_t va[16];
      if (needcheck) {
        // retry until no dword is the 0xFFFFFFFF sentinel (data-poll sync)
        while (true) {
#pragma unroll
          for (int j = 0; j < 16; ++j) va[j] = load_cv16(ap + half * 512 + 32 * j);
          asm volatile("s_waitcnt vmcnt(0)" ::: "memory");
          unsigned mx = 0u;
#pragma unroll
          for (int j = 0; j < 16; ++j)
#pragma unroll
            for (int d = 0; d < 4; ++d) {
              unsigned u = __float_as_uint(va[j][d]);
              mx = (u > mx) ? u : mx;
            }
          if (__all(mx != 0xFFFFFFFFu)) break;
          asm volatile("s_sleep 2");       // ~128 cyc backoff, cap retry traffic
        }
      } else {
#pragma unroll
        for (int j = 0; j < 16; ++j) va[j] = load_cv16(ap + half * 512 + 32 * j);
        asm volatile("s_waitcnt vmcnt(0)" ::: "memory");
      }
#pragma unroll
      for (int ks = 0; ks < 8; ++ks) {
        half8_t a0  = __builtin_bit_cast(half8_t, va[2 * ks]);
        half8_t a1  = __builtin_bit_cast(half8_t, va[2 * ks + 1]);
        half8_t bv0 = *(const half8_t*)(smem + boff);
        half8_t bv1 = *(const half8_t*)(smem + boff + 1024);
        acc0 = __builtin_amdgcn_mfma_f32_32x32x16_f16(a0, bv0, acc0, 0, 0, 0);
        acc1 = __builtin_amdgcn_mfma_f32_32x32x16_f16(a1, bv1, acc1, 0, 0, 0);
        boff += 2048;
      }
    }

    // ---- C frags -> LDS red[w][row][33] (row = (r&3)+8*(r>>2)+4*(l>>5)) ----
    {
      float* redw = red + w * 1056 + (l & 31);
      const int rbase = (l >> 5) << 2;
#pragma unroll
      for (int r = 0; r < 16; ++r) {
        int row = (r & 3) + ((r >> 2) << 3) + rbase;
        redw[row * 33] = acc0[r] + acc1[r];
      }
    }
    __syncthreads();

    // ---- cell update: thread owns (cbl, j0) and (cbl, j0+1); c in regs ----
    {
      const int base = (cbl >> 5) * 1056 + (cbl & 31) * 33 + j0;
      float hv[2];
#pragma unroll
      for (int p = 0; p < 2; ++p) {
        float vi = red[base + p]      + red[base + 2112 + p]      + (layer ? bias1[0][p] : bias0[0][p]);
        float vf = red[base + 8 + p]  + red[base + 2112 + 8 + p]  + (layer ? bias1[1][p] : bias0[1][p]);
        float vg = red[base + 16 + p] + red[base + 2112 + 16 + p] + (layer ? bias1[2][p] : bias0[2][p]);
        float vo = red[base + 24 + p] + red[base + 2112 + 24 + p] + (layer ? bias1[3][p] : bias0[3][p]);
        float iv = sigmoidf_(vi), fv = sigmoidf_(vf);
        float gv = tanhf_(vg),    ov = sigmoidf_(vo);
        float cold = layer ? c1s[p] : c0s[p];
        float c = fv * cold + iv * gv;
        if (layer) c1s[p] = c; else c0s[p] = c;
        hv[p] = ov * tanhf_(c);
      }
      const int gidx = (b0 + cbl) * 512 + d0 + j0;
      unsigned hu = ((unsigned)__builtin_bit_cast(unsigned short, (_Float16)hv[0])) |
                    ((unsigned)__builtin_bit_cast(unsigned short, (_Float16)hv[1]) << 16);
      STOREC((unsigned*)&hout[gidx], hu);   // sc0 sc1 store IS the release
      if (layer) {                          // plain store, acks at L2 fast
        float* op = out + (size_t)t * BD + gidx;
        op[0] = hv[0]; op[1] = hv[1];
      }
    }
    __syncthreads();   // red[] reuse ordering only — no drain, no flag
  }
}

extern "C" void kernel_launch(void* const* d_in, const int* in_sizes, int n_in,
                              void* d_out, int out_size, void* d_ws, size_t ws_size,
                              hipStream_t stream) {
  const float* h    = (const float*)d_in[0];
  // d_in[1] = T (== 64, compile-time)
  const float* Wih0 = (const float*)d_in[2];
  const float* Whh0 = (const float*)d_in[3];
  const float* bih0 = (const float*)d_in[4];
  const float* bhh0 = (const float*)d_in[5];
  const float* Wih1 = (const float*)d_in[6];
  const float* Whh1 = (const float*)d_in[7];
  const float* bih1 = (const float*)d_in[8];
  const float* bhh1 = (const float*)d_in[9];
  float* out = (float*)d_out;
  char* ws = (char*)d_ws;

  if (ws_size < (size_t)WS_NEED) return;   // R8 proved ws >= 34 MB; fail loud

  hipFuncSetAttribute((const void*)lstm_persist,
                      hipFuncAttributeMaxDynamicSharedMemorySize, SMEM_BYTES);

  lstm_init<<<2048, 256, 0, stream>>>(h, ws);

  // Plain launch: no cross-WG waits by producers, no grid barriers —
  // dispatch-order-safe by construction.
  lstm_persist<<<256, 256, SMEM_BYTES, stream>>>(Wih0, Whh0, bih0, bhh0,
                                                 Wih1, Whh1, bih1, bhh1,
                                                 out, ws);
}